// Round 1
// baseline (2985.905 us; speedup 1.0000x reference)
//
#include <hip/hip_runtime.h>

#define BROWS 32768
#define DIM   512
#define NK    1024
#define NL    4

// ---------------------------------------------------------------------------
// k_pre: c2[l*NK+k] = sum(cb[l,k,:]^2) for all 4096 codes; zero the loss slot.
// One 64-thread block per code; coalesced float4 reads; wave shuffle reduce.
// ---------------------------------------------------------------------------
__global__ __launch_bounds__(64) void k_pre(const float* __restrict__ cb,
                                            float* __restrict__ c2all,
                                            float* __restrict__ loss_slot) {
  const int code = blockIdx.x;           // 0..4095
  const int lane = threadIdx.x;          // 0..63
  const float4* c4 = (const float4*)(cb + (size_t)code * DIM);
  float s = 0.f;
#pragma unroll
  for (int j = 0; j < 2; ++j) {
    float4 v = c4[lane + j * 64];
    s += v.x * v.x + v.y * v.y + v.z * v.z + v.w * v.w;
  }
#pragma unroll
  for (int m = 1; m < 64; m <<= 1) s += __shfl_xor(s, m, 64);
  if (lane == 0) c2all[code] = s;
  if (code == 0 && lane == 0) *loss_slot = 0.f;
}

// ---------------------------------------------------------------------------
// k_r2: r2[row] = sum(z[row,:]^2). 8 rows per 256-thread block (32 lanes/row).
// ---------------------------------------------------------------------------
__global__ __launch_bounds__(256) void k_r2(const float* __restrict__ R,
                                            float* __restrict__ r2) {
  const int t = threadIdx.x;
  const int row = blockIdx.x * 8 + (t >> 5);
  const int lane = t & 31;
  const float4* r4 = (const float4*)(R + (size_t)row * DIM);
  float s = 0.f;
#pragma unroll
  for (int j = 0; j < 4; ++j) {
    float4 v = r4[lane + j * 32];
    s += v.x * v.x + v.y * v.y + v.z * v.z + v.w * v.w;
  }
#pragma unroll
  for (int m = 1; m < 32; m <<= 1) s += __shfl_xor(s, m, 64);
  if (lane == 0) r2[row] = s;
}

// ---------------------------------------------------------------------------
// k_gemm: scores = residual @ cb_l^T  (M=32768, N=1024, K=512) with fused
// dist = (r2 - 2*dot) + c2 (replicates np op order) and per-row argmin over
// this block's 128 codes. Writes (min,idx) partials per (row, n-block).
// Tile: BM=BN=128, BK=16, 256 threads, 8x8 acc/thread, double-buffered LDS.
// ---------------------------------------------------------------------------
__global__ __launch_bounds__(256) void k_gemm(const float* __restrict__ R,
                                              const float* __restrict__ CB,
                                              const float* __restrict__ r2v,
                                              const float* __restrict__ c2v,
                                              float* __restrict__ pmin,
                                              int* __restrict__ pidx) {
  __shared__ float As[2][16][128];   // [buf][k][m]
  __shared__ float Bs[2][16][128];   // [buf][k][n]
  __shared__ float redm[128][16];
  __shared__ int   redi[128][16];

  const int t = threadIdx.x;
  const int nb = blockIdx.x;         // 0..7   (col tile)
  const int mb = blockIdx.y;         // 0..255 (row tile)
  const int rowBase = mb * 128, colBase = nb * 128;
  const int tx = t & 15, ty = t >> 4;

  // staging: 2048 floats per tile = 2 float4 per thread per matrix
  const int f1 = t + 256;
  const int ar0 = t >> 2,  ak0 = (t & 3) * 4;
  const int ar1 = f1 >> 2, ak1 = (f1 & 3) * 4;

  const float* A0 = R  + (size_t)(rowBase + ar0) * DIM + ak0;
  const float* A1 = R  + (size_t)(rowBase + ar1) * DIM + ak1;
  const float* B0 = CB + (size_t)(colBase + ar0) * DIM + ak0;
  const float* B1 = CB + (size_t)(colBase + ar1) * DIM + ak1;

  float4 a0v, a1v, b0v, b1v;
  float acc[8][8];
#pragma unroll
  for (int i = 0; i < 8; ++i)
#pragma unroll
    for (int j = 0; j < 8; ++j) acc[i][j] = 0.f;

  auto ldglobal = [&](int kt) {
    const int off = kt * 16;
    a0v = *(const float4*)(A0 + off);
    a1v = *(const float4*)(A1 + off);
    b0v = *(const float4*)(B0 + off);
    b1v = *(const float4*)(B1 + off);
  };
  auto st_lds = [&](int buf) {
#pragma unroll
    for (int j = 0; j < 4; ++j) {
      As[buf][ak0 + j][ar0] = (&a0v.x)[j];
      As[buf][ak1 + j][ar1] = (&a1v.x)[j];
      Bs[buf][ak0 + j][ar0] = (&b0v.x)[j];
      Bs[buf][ak1 + j][ar1] = (&b1v.x)[j];
    }
  };

  ldglobal(0);
  st_lds(0);
  __syncthreads();

  for (int kt = 0; kt < 32; ++kt) {
    const int cur = kt & 1;
    if (kt + 1 < 32) ldglobal(kt + 1);
#pragma unroll
    for (int kk = 0; kk < 16; ++kk) {
      float4 x0 = *(const float4*)&As[cur][kk][ty * 4];
      float4 x1 = *(const float4*)&As[cur][kk][64 + ty * 4];
      float4 y0 = *(const float4*)&Bs[cur][kk][tx * 4];
      float4 y1 = *(const float4*)&Bs[cur][kk][64 + tx * 4];
      float a[8] = {x0.x, x0.y, x0.z, x0.w, x1.x, x1.y, x1.z, x1.w};
      float b[8] = {y0.x, y0.y, y0.z, y0.w, y1.x, y1.y, y1.z, y1.w};
#pragma unroll
      for (int i = 0; i < 8; ++i)
#pragma unroll
        for (int j = 0; j < 8; ++j) acc[i][j] = fmaf(a[i], b[j], acc[i][j]);
    }
    if (kt + 1 < 32) st_lds(cur ^ 1);
    __syncthreads();
  }

  // Epilogue: dist + per-thread argmin (ascending code order -> strict <
  // keeps first index), then cross-thread reduce with first-index tie-break.
  float r2r[8], c2c[8];
#pragma unroll
  for (int i = 0; i < 8; ++i) {
    const int lr = ty * 4 + (i & 3) + 64 * (i >> 2);
    r2r[i] = r2v[rowBase + lr];
  }
#pragma unroll
  for (int j = 0; j < 8; ++j) {
    const int lc = tx * 4 + (j & 3) + 64 * (j >> 2);
    c2c[j] = c2v[colBase + lc];
  }
#pragma unroll
  for (int i = 0; i < 8; ++i) {
    float bm = 3.4e38f;
    int bi = 0x7fffffff;
#pragma unroll
    for (int j = 0; j < 8; ++j) {
      const int col = colBase + tx * 4 + (j & 3) + 64 * (j >> 2);
      // np op order: (r2 - 2*dot) + c2, each step fp32-rounded
      const float dist = (r2r[i] - 2.0f * acc[i][j]) + c2c[j];
      if (dist < bm || (dist == bm && col < bi)) { bm = dist; bi = col; }
    }
    const int lr = ty * 4 + (i & 3) + 64 * (i >> 2);
    redm[lr][tx] = bm;
    redi[lr][tx] = bi;
  }
  __syncthreads();
  if (t < 128) {
    float bm = 3.4e38f;
    int bi = 0x7fffffff;
#pragma unroll
    for (int x = 0; x < 16; ++x) {
      const float m = redm[t][x];
      const int i = redi[t][x];
      if (m < bm || (m == bm && i < bi)) { bm = m; bi = i; }
    }
    pmin[(size_t)nb * BROWS + rowBase + t] = bm;
    pidx[(size_t)nb * BROWS + rowBase + t] = bi;
  }
}

// ---------------------------------------------------------------------------
// k_update: finalize argmin over 8 n-block partials, gather chosen codebook
// row, write chosen into alv[l] (aliases Rin for l>=1: read-before-write per
// thread), write residual_{l+1} into alv[l+1] (staging), accumulate loss and
// next-level r2. Last level: write quantized = z - residual_final instead.
// 8 rows per 256-thread block (32 lanes per row).
// ---------------------------------------------------------------------------
__global__ __launch_bounds__(256) void k_update(const float* __restrict__ Rin,
                                                const float* __restrict__ CB,
                                                const float* __restrict__ pmin,
                                                const int* __restrict__ pidx,
                                                float* __restrict__ chosen_out,
                                                float* __restrict__ Rout,
                                                float* __restrict__ r2out,
                                                float* __restrict__ loss,
                                                const float* __restrict__ Z,
                                                float* __restrict__ Q,
                                                int last) {
  __shared__ float ls[8];
  const int t = threadIdx.x;
  const int rrow = t >> 5, lane = t & 31;
  const int row = blockIdx.x * 8 + rrow;

  // final argmin across the 8 column-block partials (first-index tie-break)
  float bm = 3.4e38f;
  int bi = 0x7fffffff;
#pragma unroll
  for (int nbk = 0; nbk < 8; ++nbk) {
    const float m = pmin[(size_t)nbk * BROWS + row];
    const int i = pidx[(size_t)nbk * BROWS + row];
    if (m < bm || (m == bm && i < bi)) { bm = m; bi = i; }
  }

  const float4* r4 = (const float4*)(Rin + (size_t)row * DIM);
  const float4* c4 = (const float4*)(CB + (size_t)bi * DIM);
  float4* ch4 = (float4*)(chosen_out + (size_t)row * DIM);
  float s = 0.f;
#pragma unroll
  for (int j = 0; j < 4; ++j) {
    const int e = lane + j * 32;
    const float4 r = r4[e];
    const float4 c = c4[e];
    float4 rn;
    rn.x = r.x - c.x; rn.y = r.y - c.y; rn.z = r.z - c.z; rn.w = r.w - c.w;
    ch4[e] = c;
    if (!last) {
      ((float4*)(Rout + (size_t)row * DIM))[e] = rn;
    } else {
      const float4 zv = ((const float4*)(Z + (size_t)row * DIM))[e];
      float4 q;
      q.x = zv.x - rn.x; q.y = zv.y - rn.y; q.z = zv.z - rn.z; q.w = zv.w - rn.w;
      ((float4*)(Q + (size_t)row * DIM))[e] = q;
    }
    s += rn.x * rn.x + rn.y * rn.y + rn.z * rn.z + rn.w * rn.w;
  }
#pragma unroll
  for (int m = 1; m < 32; m <<= 1) s += __shfl_xor(s, m, 64);
  if (lane == 0) {
    if (!last) r2out[row] = s;
    ls[rrow] = s;
  }
  __syncthreads();
  if (t == 0) {
    float tot = 0.f;
#pragma unroll
    for (int i = 0; i < 8; ++i) tot += ls[i];
    atomicAdd(loss, tot * (1.0f / 16777216.0f));  // / (B*D), exact 2^-24
  }
}

// ---------------------------------------------------------------------------
extern "C" void kernel_launch(void* const* d_in, const int* in_sizes, int n_in,
                              void* d_out, int out_size, void* d_ws, size_t ws_size,
                              hipStream_t stream) {
  const float* z  = (const float*)d_in[0];   // [32768, 512]
  const float* cb = (const float*)d_in[1];   // [4, 1024, 512]

  float* q    = (float*)d_out;                                  // [B, D]
  float* alv  = (float*)d_out + (size_t)BROWS * DIM;            // [L, B, D]
  float* loss = (float*)d_out + (size_t)BROWS * DIM * (NL + 1); // scalar

  // workspace carve (~2.2 MB)
  float* c2all = (float*)d_ws;                  // [NL*NK]
  float* r2ws  = c2all + NL * NK;               // [BROWS]
  float* pmin  = r2ws + BROWS;                  // [8 * BROWS]
  int*   pidx  = (int*)(pmin + 8 * BROWS);      // [8 * BROWS]

  k_pre<<<NL * NK, 64, 0, stream>>>(cb, c2all, loss);
  k_r2<<<BROWS / 8, 256, 0, stream>>>(z, r2ws);

  for (int l = 0; l < NL; ++l) {
    const float* R   = (l == 0) ? z : (alv + (size_t)l * BROWS * DIM);
    const float* cbl = cb + (size_t)l * NK * DIM;
    k_gemm<<<dim3(8, 256), 256, 0, stream>>>(R, cbl, r2ws, c2all + l * NK,
                                             pmin, pidx);
    const int last = (l == NL - 1);
    float* chosen = alv + (size_t)l * BROWS * DIM;
    float* Rout   = last ? nullptr : (alv + (size_t)(l + 1) * BROWS * DIM);
    k_update<<<BROWS / 8, 256, 0, stream>>>(R, cbl, pmin, pidx, chosen, Rout,
                                            r2ws, loss, z, q, last);
  }
}